// Round 15
// baseline (207.989 us; speedup 1.0000x reference)
//
#include <hip/hip_runtime.h>

typedef __bf16 bf16x4 __attribute__((ext_vector_type(4)));
typedef __bf16 bf16x8 __attribute__((ext_vector_type(8)));
typedef float f32x16 __attribute__((ext_vector_type(16)));

// ---- workspace layout (bf16 element offsets), FRAGMENT-ORDERED weights ----
// A wave's weight frag for (n-tile, k-block) is 64 lanes x 16 B = 1 KB contig:
//   elem (lane, j) at ((nt*NKBLK + kk)*64 + lane)*8 + j
//   encodes n = nt*32 + (lane&31), k = kk*16 + (lane>>5)*8 + j
#define W0F_OFF 0                 // 16 nt x 1 kk  x 64 x 8  = 8192
#define W1F_OFF 8192              // 16 nt x 32 kk x 64 x 8  = 262144
#define W2F_OFF (8192 + 262144)   // 5 nt  x 32 kk x 64 x 8  = 81920 (n>=136 zero)
#define PREP_TOTAL (8192 + 262144 + 81920)

__global__ void prep_weights(const float* __restrict__ W0,
                             const float* __restrict__ W1,
                             const float* __restrict__ W2,
                             __bf16* __restrict__ ws) {
    int t = blockIdx.x * 256 + threadIdx.x;
    if (t < 8192) {
        int j = t & 7, lane = (t >> 3) & 63, nt = t >> 9;
        int n = nt * 32 + (lane & 31);
        int k = (lane >> 5) * 8 + j;              // < 16
        ws[W0F_OFF + t] = (__bf16)W0[k * 512 + n];
    } else if (t < 8192 + 262144) {
        int u = t - 8192;
        int j = u & 7, lane = (u >> 3) & 63;
        int x = u >> 9;                            // nt*32 + kk
        int kk = x & 31, nt = x >> 5;
        int n = nt * 32 + (lane & 31);
        int k = kk * 16 + (lane >> 5) * 8 + j;
        ws[W1F_OFF + u] = (__bf16)W1[k * 512 + n];
    } else if (t < PREP_TOTAL) {
        int v = t - (8192 + 262144);
        int j = v & 7, lane = (v >> 3) & 63;
        int x = v >> 9;                            // nt*32 + kk
        int kk = x & 31, nt = x >> 5;
        int n = nt * 32 + (lane & 31);
        int k = kk * 16 + (lane >> 5) * 8 + j;
        ws[W2F_OFF + v] = (n < 136) ? (__bf16)W2[k * 136 + n] : (__bf16)0.0f;
    }
}

__device__ __forceinline__ float fast_tanh(float x) {
#if __has_builtin(__builtin_amdgcn_exp2f)
    float e = __builtin_amdgcn_exp2f(x * 2.885390081777926f);
#else
    float e = exp2f(x * 2.885390081777926f);
#endif
    return 1.0f - 2.0f * __builtin_amdgcn_rcpf(e + 1.0f);
}

// h LDS: [64][520] bf16 (rows 1040 B, 16B-aligned), imm-offset ds_read_b128.
#define HSTR 520
// net LDS: [64][140] f32 overlay (float4-aligned rows).
#define NSTR 140

// R15: R14 (BM=64, 8 waves, 2nt x 2bt, acc=64 AGPR, operand-swapped MFMA)
// + batch-4 super-iterations. R14's VGPR=64 arch showed the compiler
// serialized loads inside each round to hit 4 waves/SIMD (8 frags alone need
// 64 regs) -> MfmaUtil capped at 33%. Batch-4 forces a 128-reg in-flight
// window: one L2 stall per 16 MFMAs (512 SIMD-cyc). Deliberately trades
// occupancy (4 -> 2-3 waves/SIMD) for per-wave latency coverage.
// acc stays 64 (R13 lesson: acc=128 -> accvgpr-shuffle VALU pathology).
// Fragment maps (m74/m101):
//   W(A): n_out = lane&31, k = (lane>>5)*8 + j
//   act(B): batch = lane&31, k = (lane>>5)*8 + j
//   D: batch = lane&31, n_out = (reg&3) + 8*(reg>>2) + 4*(lane>>5)
__global__ __launch_bounds__(512, 2)
void fused_mlp_quad(const float* __restrict__ points,
                    const float* __restrict__ b0,
                    const float* __restrict__ b1,
                    const float* __restrict__ b2,
                    const __bf16* __restrict__ ws,
                    float* __restrict__ out) {
    __shared__ __align__(16) unsigned char lds_raw[66560];
    __bf16* h  = (__bf16*)lds_raw;   // [64][HSTR] bf16 (h0, then h1 in place)
    float* net = (float*)lds_raw;    // [64][NSTR] f32 overlay after phase 2

    const __bf16* w0f = ws + W0F_OFF;
    const __bf16* w1f = ws + W1F_OFF;
    const __bf16* w2f = ws + W2F_OFF;

    const int tid = threadIdx.x;
    const int w   = tid >> 6;     // wave 0..7
    const int l   = tid & 63;
    const int ln  = l & 31;       // batch row within tile / 32x32 lane index
    const int hi  = l >> 5;       // k-half
    const int row0 = blockIdx.x * 64;

    const int lofs = l * 8;       // lane offset within a 1KB fragment record

    // ---------- phase 0: h0 = tanh(x @ W0 + b0), K=16 = one MFMA step ----------
    {
        bf16x8 bx[2];
#pragma unroll
        for (int bt = 0; bt < 2; ++bt) {
            const float* src = points + (row0 + bt * 32 + ln) * 16 + hi * 8;
            float4 p0 = ((const float4*)src)[0];
            float4 p1 = ((const float4*)src)[1];
            bf16x8 v;
            v[0] = (__bf16)p0.x; v[1] = (__bf16)p0.y; v[2] = (__bf16)p0.z; v[3] = (__bf16)p0.w;
            v[4] = (__bf16)p1.x; v[5] = (__bf16)p1.y; v[6] = (__bf16)p1.z; v[7] = (__bf16)p1.w;
            bx[bt] = v;
        }
#pragma unroll
        for (int t = 0; t < 2; ++t) {
            const int ntg = w * 2 + t;
            bf16x8 wf = *(const bf16x8*)(w0f + ntg * 512 + lofs);
#pragma unroll
            for (int bt = 0; bt < 2; ++bt) {
                f32x16 acc = {};
                acc = __builtin_amdgcn_mfma_f32_32x32x16_bf16(wf, bx[bt], acc, 0, 0, 0);
#pragma unroll
                for (int rg = 0; rg < 4; ++rg) {
                    const int n0 = ntg * 32 + 8 * rg + 4 * hi;
                    float4 bias = *(const float4*)(b0 + n0);
                    bf16x4 v;
                    v[0] = (__bf16)fast_tanh(acc[4 * rg + 0] + bias.x);
                    v[1] = (__bf16)fast_tanh(acc[4 * rg + 1] + bias.y);
                    v[2] = (__bf16)fast_tanh(acc[4 * rg + 2] + bias.z);
                    v[3] = (__bf16)fast_tanh(acc[4 * rg + 3] + bias.w);
                    *(bf16x4*)(h + (bt * 32 + ln) * HSTR + n0) = v;
                }
            }
        }
    }
    __syncthreads();

    // ---------- phase 1: h1 = tanh(h0 @ W1 + b1) ----------
    // wave: 2 nt x 2 bt; acc = 64 AGPR. Batch-4: 8 weight frags + 8 act
    // frags (128 regs) in flight, then 16 MFMAs per L2 round-trip.
    f32x16 acc1[2][2] = {};   // [bt][t]
    {
        const __bf16* arow0 = h + ln * HSTR + hi * 8;          // bt=0
        const __bf16* arow1 = h + (32 + ln) * HSTR + hi * 8;   // bt=1
        const __bf16* wb0 = w1f + (w * 2 + 0) * 16384 + lofs;
        const __bf16* wb1 = w1f + (w * 2 + 1) * 16384 + lofs;
        for (int ks = 0; ks < 8; ++ks) {
            bf16x8 aa[4][2], bb[4][2];
#pragma unroll
            for (int u = 0; u < 4; ++u) {
                const int kk = ks * 4 + u;
                const int vo = kk * 512;
                aa[u][0] = *(const bf16x8*)(arow0 + kk * 16);
                aa[u][1] = *(const bf16x8*)(arow1 + kk * 16);
                bb[u][0] = *(const bf16x8*)(wb0 + vo);
                bb[u][1] = *(const bf16x8*)(wb1 + vo);
            }
#pragma unroll
            for (int u = 0; u < 4; ++u) {
#pragma unroll
                for (int t = 0; t < 2; ++t) {
                    acc1[0][t] = __builtin_amdgcn_mfma_f32_32x32x16_bf16(bb[u][t], aa[u][0], acc1[0][t], 0, 0, 0);
                    acc1[1][t] = __builtin_amdgcn_mfma_f32_32x32x16_bf16(bb[u][t], aa[u][1], acc1[1][t], 0, 0, 0);
                }
            }
        }
    }
    __syncthreads();   // all h0 reads done; overwrite in place
#pragma unroll
    for (int t = 0; t < 2; ++t) {
#pragma unroll
        for (int bt = 0; bt < 2; ++bt) {
#pragma unroll
            for (int rg = 0; rg < 4; ++rg) {
                const int n0 = (w * 2 + t) * 32 + 8 * rg + 4 * hi;
                float4 bias = *(const float4*)(b1 + n0);
                bf16x4 v;
                v[0] = (__bf16)fast_tanh(acc1[bt][t][4 * rg + 0] + bias.x);
                v[1] = (__bf16)fast_tanh(acc1[bt][t][4 * rg + 1] + bias.y);
                v[2] = (__bf16)fast_tanh(acc1[bt][t][4 * rg + 2] + bias.z);
                v[3] = (__bf16)fast_tanh(acc1[bt][t][4 * rg + 3] + bias.w);
                *(bf16x4*)(h + (bt * 32 + ln) * HSTR + n0) = v;
            }
        }
    }
    __syncthreads();

    // ---------- phase 2: net = h1 @ W2 + b2 (N pad 160: 5 nt x 2 bt = 10 tiles) ----
    // wave w: tile (nt = w>>1, bt = w&1); waves 0,1 also tile (nt=4, bt=w).
    f32x16 acc2a = {}, acc2e = {};
    const int nt2 = w >> 1;
    const int bt2 = w & 1;
    const bool two = (w < 2);
    {
        const __bf16* arowA = h + (bt2 * 32 + ln) * HSTR + hi * 8;
        const __bf16* arowE = h + ((w & 1) * 32 + ln) * HSTR + hi * 8;  // bt=w for w<2
        const __bf16* wbA = w2f + nt2 * 16384 + lofs;
        const __bf16* wbE = w2f + 4 * 16384 + lofs;
        for (int ks = 0; ks < 8; ++ks) {
            bf16x8 aaA[4], wA[4], aaE[4], wE[4];
#pragma unroll
            for (int u = 0; u < 4; ++u) {
                const int kk = ks * 4 + u;
                const int vo = kk * 512;
                aaA[u] = *(const bf16x8*)(arowA + kk * 16);
                wA[u]  = *(const bf16x8*)(wbA + vo);
                if (two) {
                    aaE[u] = *(const bf16x8*)(arowE + kk * 16);
                    wE[u]  = *(const bf16x8*)(wbE + vo);
                }
            }
#pragma unroll
            for (int u = 0; u < 4; ++u) {
                acc2a = __builtin_amdgcn_mfma_f32_32x32x16_bf16(wA[u], aaA[u], acc2a, 0, 0, 0);
                if (two)
                    acc2e = __builtin_amdgcn_mfma_f32_32x32x16_bf16(wE[u], aaE[u], acc2e, 0, 0, 0);
            }
        }
    }
    __syncthreads();   // all h1 reads done; overwrite with net (fp32)
    {
#pragma unroll
        for (int rg = 0; rg < 4; ++rg) {
            const int n0 = nt2 * 32 + 8 * rg + 4 * hi;   // <= 127 < 136
            float4 bias = *(const float4*)(b2 + n0);
            float4 v;
            v.x = acc2a[4 * rg + 0] + bias.x;
            v.y = acc2a[4 * rg + 1] + bias.y;
            v.z = acc2a[4 * rg + 2] + bias.z;
            v.w = acc2a[4 * rg + 3] + bias.w;
            *(float4*)(net + (bt2 * 32 + ln) * NSTR + n0) = v;
        }
        if (two) {
            // extra tile nt=4 (n 128..135): only rg==0 in range (n0=128/132)
            const int n0 = 128 + 4 * hi;
            float4 bias = *(const float4*)(b2 + n0);
            float4 v;
            v.x = acc2e[0] + bias.x;
            v.y = acc2e[1] + bias.y;
            v.z = acc2e[2] + bias.z;
            v.w = acc2e[3] + bias.w;
            *(float4*)(net + (w * 32 + ln) * NSTR + n0) = v;
        }
    }
    __syncthreads();

    // ---------- phase 3: vals = ||M^T x||^2 + eps*||x||^2 ----------
    // 8 threads per row x 64 rows = 512 threads, single pass
    {
        const int r  = tid >> 3;
        const int jg = tid & 7;
        const float* xp = points + (row0 + r) * 16;
        float xv[16];
#pragma unroll
        for (int i = 0; i < 4; ++i) {
            float4 v = ((const float4*)xp)[i];
            xv[i * 4 + 0] = v.x; xv[i * 4 + 1] = v.y;
            xv[i * 4 + 2] = v.z; xv[i * 4 + 3] = v.w;
        }
        float sumsq = 0.f;
#pragma unroll
        for (int i = 0; i < 16; ++i) sumsq += xv[i] * xv[i];
        float p = 0.f;
#pragma unroll
        for (int jj = 0; jj < 2; ++jj) {
            const int j = jg + jj * 8;
            float y = 0.f;
#pragma unroll
            for (int i = 0; i < 16; ++i) {
                float mv = net[r * NSTR + ((i * (i + 1)) >> 1) + j];
                y += (i >= j) ? mv * xv[i] : 0.f;
            }
            p += y * y;
        }
        p += __shfl_xor(p, 1);
        p += __shfl_xor(p, 2);
        p += __shfl_xor(p, 4);
        if (jg == 0) out[row0 + r] = p + 1e-6f * sumsq;
    }
}

extern "C" void kernel_launch(void* const* d_in, const int* in_sizes, int n_in,
                              void* d_out, int out_size, void* d_ws, size_t ws_size,
                              hipStream_t stream) {
    const float* points = (const float*)d_in[0];
    const float* W0 = (const float*)d_in[1];
    const float* b0 = (const float*)d_in[2];
    const float* W1 = (const float*)d_in[3];
    const float* b1 = (const float*)d_in[4];
    const float* W2 = (const float*)d_in[5];
    const float* b2 = (const float*)d_in[6];
    __bf16* ws = (__bf16*)d_ws;
    float* out = (float*)d_out;

    prep_weights<<<(PREP_TOTAL + 255) / 256, 256, 0, stream>>>(W0, W1, W2, ws);

    const int B = in_sizes[0] / 16;   // 131072
    fused_mlp_quad<<<B / 64, 512, 0, stream>>>(points, b0, b1, b2, ws, out);
}

// Round 16
// 198.280 us; speedup vs baseline: 1.0490x; 1.0490x over previous
//
#include <hip/hip_runtime.h>

typedef __bf16 bf16x4 __attribute__((ext_vector_type(4)));
typedef __bf16 bf16x8 __attribute__((ext_vector_type(8)));
typedef float f32x16 __attribute__((ext_vector_type(16)));

// ---- workspace layout (bf16 element offsets), FRAGMENT-ORDERED weights ----
// A wave's weight frag for (n-tile, k-block) is 64 lanes x 16 B = 1 KB contig:
//   elem (lane, j) at ((nt*NKBLK + kk)*64 + lane)*8 + j
//   encodes n = nt*32 + (lane&31), k = kk*16 + (lane>>5)*8 + j
#define W0F_OFF 0                 // 16 nt x 1 kk  x 64 x 8  = 8192
#define W1F_OFF 8192              // 16 nt x 32 kk x 64 x 8  = 262144
#define W2F_OFF (8192 + 262144)   // 5 nt  x 32 kk x 64 x 8  = 81920 (n>=136 zero)
#define PREP_TOTAL (8192 + 262144 + 81920)

__global__ void prep_weights(const float* __restrict__ W0,
                             const float* __restrict__ W1,
                             const float* __restrict__ W2,
                             __bf16* __restrict__ ws) {
    int t = blockIdx.x * 256 + threadIdx.x;
    if (t < 8192) {
        int j = t & 7, lane = (t >> 3) & 63, nt = t >> 9;
        int n = nt * 32 + (lane & 31);
        int k = (lane >> 5) * 8 + j;              // < 16
        ws[W0F_OFF + t] = (__bf16)W0[k * 512 + n];
    } else if (t < 8192 + 262144) {
        int u = t - 8192;
        int j = u & 7, lane = (u >> 3) & 63;
        int x = u >> 9;                            // nt*32 + kk
        int kk = x & 31, nt = x >> 5;
        int n = nt * 32 + (lane & 31);
        int k = kk * 16 + (lane >> 5) * 8 + j;
        ws[W1F_OFF + u] = (__bf16)W1[k * 512 + n];
    } else if (t < PREP_TOTAL) {
        int v = t - (8192 + 262144);
        int j = v & 7, lane = (v >> 3) & 63;
        int x = v >> 9;                            // nt*32 + kk
        int kk = x & 31, nt = x >> 5;
        int n = nt * 32 + (lane & 31);
        int k = kk * 16 + (lane >> 5) * 8 + j;
        ws[W2F_OFF + v] = (n < 136) ? (__bf16)W2[k * 136 + n] : (__bf16)0.0f;
    }
}

__device__ __forceinline__ float fast_tanh(float x) {
#if __has_builtin(__builtin_amdgcn_exp2f)
    float e = __builtin_amdgcn_exp2f(x * 2.885390081777926f);
#else
    float e = exp2f(x * 2.885390081777926f);
#endif
    return 1.0f - 2.0f * __builtin_amdgcn_rcpf(e + 1.0f);
}

// h LDS: [128][520] bf16 (rows 1040 B, 16B-aligned), imm-offset ds_read_b128.
#define HSTR 520
// net LDS: [128][140] f32 overlay (float4-aligned rows).
#define NSTR 140

// R16: BM=128, 1024 threads (16 waves, 4/SIMD, 1 block/CU; LDS 133 KB).
// R14 analysis: at 4 waves/SIMD the limiter was per-CU L2/TCP weight traffic
// (~1.3 MB per 128 rows -> ~73 us). BM=128 halves it (~17 us) AND phase 1
// becomes one n-tile per wave: 1 global weight frag per 4 MFMAs (was 1:2),
// so batch-4 weight prefetch costs only 32 regs. acc = 64 AGPR (R13 lesson:
// acc=128 -> accvgpr-shuffle pathology). __launch_bounds__(1024,4) = the
// R14-proven 128-reg/wave envelope (VGPR=64, no spill).
// Fragment maps (m74/m101):
//   W(A): n_out = lane&31, k = (lane>>5)*8 + j
//   act(B): batch = lane&31, k = (lane>>5)*8 + j
//   D: batch = lane&31, n_out = (reg&3) + 8*(reg>>2) + 4*(lane>>5)
__global__ __launch_bounds__(1024, 4)
void fused_mlp_quad(const float* __restrict__ points,
                    const float* __restrict__ b0,
                    const float* __restrict__ b1,
                    const float* __restrict__ b2,
                    const __bf16* __restrict__ ws,
                    float* __restrict__ out) {
    __shared__ __align__(16) unsigned char lds_raw[133120];
    __bf16* h  = (__bf16*)lds_raw;   // [128][HSTR] bf16 (h0, then h1 in place)
    float* net = (float*)lds_raw;    // [128][NSTR] f32 overlay after phase 2

    const __bf16* w0f = ws + W0F_OFF;
    const __bf16* w1f = ws + W1F_OFF;
    const __bf16* w2f = ws + W2F_OFF;

    const int tid = threadIdx.x;
    const int w   = tid >> 6;     // wave 0..15
    const int l   = tid & 63;
    const int ln  = l & 31;       // batch row within tile / 32x32 lane index
    const int hi  = l >> 5;       // k-half
    const int row0 = blockIdx.x * 128;

    const int lofs = l * 8;       // lane offset within a 1KB fragment record

    // ---------- phase 0: h0 = tanh(x @ W0 + b0), K=16 = one MFMA step ----------
    // wave w owns n-tile w; 4 batch-tiles sequentially (one acc live at a time)
    {
        bf16x8 wf = *(const bf16x8*)(w0f + w * 512 + lofs);
#pragma unroll
        for (int bt = 0; bt < 4; ++bt) {
            const float* src = points + (row0 + bt * 32 + ln) * 16 + hi * 8;
            float4 p0 = ((const float4*)src)[0];
            float4 p1 = ((const float4*)src)[1];
            bf16x8 bx;
            bx[0] = (__bf16)p0.x; bx[1] = (__bf16)p0.y; bx[2] = (__bf16)p0.z; bx[3] = (__bf16)p0.w;
            bx[4] = (__bf16)p1.x; bx[5] = (__bf16)p1.y; bx[6] = (__bf16)p1.z; bx[7] = (__bf16)p1.w;
            f32x16 acc = {};
            acc = __builtin_amdgcn_mfma_f32_32x32x16_bf16(wf, bx, acc, 0, 0, 0);
#pragma unroll
            for (int rg = 0; rg < 4; ++rg) {
                const int n0 = w * 32 + 8 * rg + 4 * hi;
                float4 bias = *(const float4*)(b0 + n0);
                bf16x4 v;
                v[0] = (__bf16)fast_tanh(acc[4 * rg + 0] + bias.x);
                v[1] = (__bf16)fast_tanh(acc[4 * rg + 1] + bias.y);
                v[2] = (__bf16)fast_tanh(acc[4 * rg + 2] + bias.z);
                v[3] = (__bf16)fast_tanh(acc[4 * rg + 3] + bias.w);
                *(bf16x4*)(h + (bt * 32 + ln) * HSTR + n0) = v;
            }
        }
    }
    __syncthreads();

    // ---------- phase 1: h1 = tanh(h0 @ W1 + b1) ----------
    // wave w: n-tile w x 4 batch-tiles; acc = 64 AGPR. Batch-4 weight
    // prefetch (32 regs); act frags from LDS per sub-step.
    f32x16 acc1[4] = {};   // [bt]
    {
        const __bf16* arow0 = h + ln * HSTR + hi * 8;
        const __bf16* arow1 = h + (32 + ln) * HSTR + hi * 8;
        const __bf16* arow2 = h + (64 + ln) * HSTR + hi * 8;
        const __bf16* arow3 = h + (96 + ln) * HSTR + hi * 8;
        const __bf16* wb = w1f + w * 16384 + lofs;
        for (int ks = 0; ks < 8; ++ks) {
            bf16x8 wf[4];
#pragma unroll
            for (int u = 0; u < 4; ++u)
                wf[u] = *(const bf16x8*)(wb + (ks * 4 + u) * 512);
#pragma unroll
            for (int u = 0; u < 4; ++u) {
                const int ko = (ks * 4 + u) * 16;
                bf16x8 a0 = *(const bf16x8*)(arow0 + ko);
                bf16x8 a1 = *(const bf16x8*)(arow1 + ko);
                bf16x8 a2 = *(const bf16x8*)(arow2 + ko);
                bf16x8 a3 = *(const bf16x8*)(arow3 + ko);
                acc1[0] = __builtin_amdgcn_mfma_f32_32x32x16_bf16(wf[u], a0, acc1[0], 0, 0, 0);
                acc1[1] = __builtin_amdgcn_mfma_f32_32x32x16_bf16(wf[u], a1, acc1[1], 0, 0, 0);
                acc1[2] = __builtin_amdgcn_mfma_f32_32x32x16_bf16(wf[u], a2, acc1[2], 0, 0, 0);
                acc1[3] = __builtin_amdgcn_mfma_f32_32x32x16_bf16(wf[u], a3, acc1[3], 0, 0, 0);
            }
        }
    }
    __syncthreads();   // all h0 reads done; overwrite in place
#pragma unroll
    for (int bt = 0; bt < 4; ++bt) {
#pragma unroll
        for (int rg = 0; rg < 4; ++rg) {
            const int n0 = w * 32 + 8 * rg + 4 * hi;
            float4 bias = *(const float4*)(b1 + n0);
            bf16x4 v;
            v[0] = (__bf16)fast_tanh(acc1[bt][4 * rg + 0] + bias.x);
            v[1] = (__bf16)fast_tanh(acc1[bt][4 * rg + 1] + bias.y);
            v[2] = (__bf16)fast_tanh(acc1[bt][4 * rg + 2] + bias.z);
            v[3] = (__bf16)fast_tanh(acc1[bt][4 * rg + 3] + bias.w);
            *(bf16x4*)(h + (bt * 32 + ln) * HSTR + n0) = v;
        }
    }
    __syncthreads();

    // ---------- phase 2: net = h1 @ W2 + b2 (N pad 160: 5 nt x 4 bt = 20 tiles) ----
    // wave w: primary (nt2 = w>>2, bt2 = w&3); waves 0..3 extra (nt=4, bt=w).
    f32x16 acc2a = {}, acc2e = {};
    const int nt2 = w >> 2;
    const int bt2 = w & 3;
    const bool two = (w < 4);
    {
        const __bf16* arowA = h + (bt2 * 32 + ln) * HSTR + hi * 8;
        const __bf16* arowE = h + ((w & 3) * 32 + ln) * HSTR + hi * 8;
        const __bf16* wbA = w2f + nt2 * 16384 + lofs;
        const __bf16* wbE = w2f + 4 * 16384 + lofs;
        for (int ks = 0; ks < 8; ++ks) {
            bf16x8 wA[4], wE[4];
#pragma unroll
            for (int u = 0; u < 4; ++u) {
                wA[u] = *(const bf16x8*)(wbA + (ks * 4 + u) * 512);
                if (two) wE[u] = *(const bf16x8*)(wbE + (ks * 4 + u) * 512);
            }
#pragma unroll
            for (int u = 0; u < 4; ++u) {
                const int ko = (ks * 4 + u) * 16;
                bf16x8 aA = *(const bf16x8*)(arowA + ko);
                acc2a = __builtin_amdgcn_mfma_f32_32x32x16_bf16(wA[u], aA, acc2a, 0, 0, 0);
                if (two) {
                    bf16x8 aE = *(const bf16x8*)(arowE + ko);
                    acc2e = __builtin_amdgcn_mfma_f32_32x32x16_bf16(wE[u], aE, acc2e, 0, 0, 0);
                }
            }
        }
    }
    __syncthreads();   // all h1 reads done; overwrite with net (fp32)
    {
#pragma unroll
        for (int rg = 0; rg < 4; ++rg) {
            const int n0 = nt2 * 32 + 8 * rg + 4 * hi;   // <= 127 < 136
            float4 bias = *(const float4*)(b2 + n0);
            float4 v;
            v.x = acc2a[4 * rg + 0] + bias.x;
            v.y = acc2a[4 * rg + 1] + bias.y;
            v.z = acc2a[4 * rg + 2] + bias.z;
            v.w = acc2a[4 * rg + 3] + bias.w;
            *(float4*)(net + (bt2 * 32 + ln) * NSTR + n0) = v;
        }
        if (two) {
            // extra tile nt=4 (n 128..135): only rg==0 in range (n0=128/132)
            const int n0 = 128 + 4 * hi;
            float4 bias = *(const float4*)(b2 + n0);
            float4 v;
            v.x = acc2e[0] + bias.x;
            v.y = acc2e[1] + bias.y;
            v.z = acc2e[2] + bias.z;
            v.w = acc2e[3] + bias.w;
            *(float4*)(net + ((w & 3) * 32 + ln) * NSTR + n0) = v;
        }
    }
    __syncthreads();

    // ---------- phase 3: vals = ||M^T x||^2 + eps*||x||^2 ----------
    // 8 threads per row x 128 rows = 1024 threads, single pass
    {
        const int r  = tid >> 3;
        const int jg = tid & 7;
        const float* xp = points + (row0 + r) * 16;
        float xv[16];
#pragma unroll
        for (int i = 0; i < 4; ++i) {
            float4 v = ((const float4*)xp)[i];
            xv[i * 4 + 0] = v.x; xv[i * 4 + 1] = v.y;
            xv[i * 4 + 2] = v.z; xv[i * 4 + 3] = v.w;
        }
        float sumsq = 0.f;
#pragma unroll
        for (int i = 0; i < 16; ++i) sumsq += xv[i] * xv[i];
        float p = 0.f;
#pragma unroll
        for (int jj = 0; jj < 2; ++jj) {
            const int j = jg + jj * 8;
            float y = 0.f;
#pragma unroll
            for (int i = 0; i < 16; ++i) {
                float mv = net[r * NSTR + ((i * (i + 1)) >> 1) + j];
                y += (i >= j) ? mv * xv[i] : 0.f;
            }
            p += y * y;
        }
        p += __shfl_xor(p, 1);
        p += __shfl_xor(p, 2);
        p += __shfl_xor(p, 4);
        if (jg == 0) out[row0 + r] = p + 1e-6f * sumsq;
    }
}

extern "C" void kernel_launch(void* const* d_in, const int* in_sizes, int n_in,
                              void* d_out, int out_size, void* d_ws, size_t ws_size,
                              hipStream_t stream) {
    const float* points = (const float*)d_in[0];
    const float* W0 = (const float*)d_in[1];
    const float* b0 = (const float*)d_in[2];
    const float* W1 = (const float*)d_in[3];
    const float* b1 = (const float*)d_in[4];
    const float* W2 = (const float*)d_in[5];
    const float* b2 = (const float*)d_in[6];
    __bf16* ws = (__bf16*)d_ws;
    float* out = (float*)d_out;

    prep_weights<<<(PREP_TOTAL + 255) / 256, 256, 0, stream>>>(W0, W1, W2, ws);

    const int B = in_sizes[0] / 16;   // 131072
    fused_mlp_quad<<<B / 128, 1024, 0, stream>>>(points, b0, b1, b2, ws, out);
}

// Round 17
// 188.645 us; speedup vs baseline: 1.1025x; 1.0511x over previous
//
#include <hip/hip_runtime.h>

typedef __bf16 bf16x4 __attribute__((ext_vector_type(4)));
typedef __bf16 bf16x8 __attribute__((ext_vector_type(8)));
typedef float f32x16 __attribute__((ext_vector_type(16)));

// ---- workspace layout (bf16 element offsets), FRAGMENT-ORDERED weights ----
// A wave's weight frag for (n-tile, k-block) is 64 lanes x 16 B = 1 KB contig:
//   elem (lane, j) at ((nt*NKBLK + kk)*64 + lane)*8 + j
//   encodes n = nt*32 + (lane&31), k = kk*16 + (lane>>5)*8 + j
#define W0F_OFF 0                 // 16 nt x 1 kk  x 64 x 8  = 8192
#define W1F_OFF 8192              // 16 nt x 32 kk x 64 x 8  = 262144
#define W2F_OFF (8192 + 262144)   // 5 nt  x 32 kk x 64 x 8  = 81920 (n>=136 zero)
#define PREP_TOTAL (8192 + 262144 + 81920)

__global__ void prep_weights(const float* __restrict__ W0,
                             const float* __restrict__ W1,
                             const float* __restrict__ W2,
                             __bf16* __restrict__ ws) {
    int t = blockIdx.x * 256 + threadIdx.x;
    if (t < 8192) {
        int j = t & 7, lane = (t >> 3) & 63, nt = t >> 9;
        int n = nt * 32 + (lane & 31);
        int k = (lane >> 5) * 8 + j;              // < 16
        ws[W0F_OFF + t] = (__bf16)W0[k * 512 + n];
    } else if (t < 8192 + 262144) {
        int u = t - 8192;
        int j = u & 7, lane = (u >> 3) & 63;
        int x = u >> 9;                            // nt*32 + kk
        int kk = x & 31, nt = x >> 5;
        int n = nt * 32 + (lane & 31);
        int k = kk * 16 + (lane >> 5) * 8 + j;
        ws[W1F_OFF + u] = (__bf16)W1[k * 512 + n];
    } else if (t < PREP_TOTAL) {
        int v = t - (8192 + 262144);
        int j = v & 7, lane = (v >> 3) & 63;
        int x = v >> 9;                            // nt*32 + kk
        int kk = x & 31, nt = x >> 5;
        int n = nt * 32 + (lane & 31);
        int k = kk * 16 + (lane >> 5) * 8 + j;
        ws[W2F_OFF + v] = (n < 136) ? (__bf16)W2[k * 136 + n] : (__bf16)0.0f;
    }
}

__device__ __forceinline__ float fast_tanh(float x) {
#if __has_builtin(__builtin_amdgcn_exp2f)
    float e = __builtin_amdgcn_exp2f(x * 2.885390081777926f);
#else
    float e = exp2f(x * 2.885390081777926f);
#endif
    return 1.0f - 2.0f * __builtin_amdgcn_rcpf(e + 1.0f);
}

// h LDS: [64][520] bf16 (rows 1040 B, 16B-aligned), ds_read_b128.
#define HSTR 520
// net LDS: [64][140] f32 overlay (float4-aligned rows).
#define NSTR 140

// R17 = R14 (the 142 us best: BM=64, 8 waves, 2nt x 2bt, acc=64 AGPR,
// operand-swapped MFMA, batch-2 super-iters, VGPR=64+64=128 -> 2 blocks/CU,
// 4 waves/SIMD) + K-LOOP ROTATION: ks = (ks2 + ofs) & 15 with
// ofs = (blockIdx>>3)&15. Rationale: all 256 CUs stream the SAME W1
// fragments in near-lockstep -> each L2 line requested by ~32 CUs/XCD at
// once -> serialized at the L2 port, inflating latency past what 4-wave TLP
// covers (R14's MfmaUtil plateaued at 33% despite arithmetic predicting
// saturation vs 300-cyc L2). Rotation de-phases the streams 16 ways within
// each XCD. fp accumulation reorder only (absmax margin 6x).
// Register-shape laws (R13/R15/R16): acc must be <= 64 AGPR; arch must stay
// <= 64 for 2-block residency; (2,2) split minimizes LDS reads/MFMA (0.5).
__global__ __launch_bounds__(512, 2)
void fused_mlp_quad(const float* __restrict__ points,
                    const float* __restrict__ b0,
                    const float* __restrict__ b1,
                    const float* __restrict__ b2,
                    const __bf16* __restrict__ ws,
                    float* __restrict__ out) {
    __shared__ __align__(16) unsigned char lds_raw[66560];
    __bf16* h  = (__bf16*)lds_raw;   // [64][HSTR] bf16 (h0, then h1 in place)
    float* net = (float*)lds_raw;    // [64][NSTR] f32 overlay after phase 2

    const __bf16* w0f = ws + W0F_OFF;
    const __bf16* w1f = ws + W1F_OFF;
    const __bf16* w2f = ws + W2F_OFF;

    const int tid = threadIdx.x;
    const int w   = tid >> 6;     // wave 0..7
    const int l   = tid & 63;
    const int ln  = l & 31;       // batch row within tile / 32x32 lane index
    const int hi  = l >> 5;       // k-half
    const int row0 = blockIdx.x * 64;

    const int lofs = l * 8;       // lane offset within a 1KB fragment record
    const int ofs16 = (blockIdx.x >> 3) & 15;   // K-rotation (16-way per XCD)
    const int ofs8  = (blockIdx.x >> 3) & 7;

    // ---------- phase 0: h0 = tanh(x @ W0 + b0), K=16 = one MFMA step ----------
    {
        bf16x8 bx[2];
#pragma unroll
        for (int bt = 0; bt < 2; ++bt) {
            const float* src = points + (row0 + bt * 32 + ln) * 16 + hi * 8;
            float4 p0 = ((const float4*)src)[0];
            float4 p1 = ((const float4*)src)[1];
            bf16x8 v;
            v[0] = (__bf16)p0.x; v[1] = (__bf16)p0.y; v[2] = (__bf16)p0.z; v[3] = (__bf16)p0.w;
            v[4] = (__bf16)p1.x; v[5] = (__bf16)p1.y; v[6] = (__bf16)p1.z; v[7] = (__bf16)p1.w;
            bx[bt] = v;
        }
#pragma unroll
        for (int t = 0; t < 2; ++t) {
            const int ntg = w * 2 + t;
            bf16x8 wf = *(const bf16x8*)(w0f + ntg * 512 + lofs);
#pragma unroll
            for (int bt = 0; bt < 2; ++bt) {
                f32x16 acc = {};
                acc = __builtin_amdgcn_mfma_f32_32x32x16_bf16(wf, bx[bt], acc, 0, 0, 0);
#pragma unroll
                for (int rg = 0; rg < 4; ++rg) {
                    const int n0 = ntg * 32 + 8 * rg + 4 * hi;
                    float4 bias = *(const float4*)(b0 + n0);
                    bf16x4 v;
                    v[0] = (__bf16)fast_tanh(acc[4 * rg + 0] + bias.x);
                    v[1] = (__bf16)fast_tanh(acc[4 * rg + 1] + bias.y);
                    v[2] = (__bf16)fast_tanh(acc[4 * rg + 2] + bias.z);
                    v[3] = (__bf16)fast_tanh(acc[4 * rg + 3] + bias.w);
                    *(bf16x4*)(h + (bt * 32 + ln) * HSTR + n0) = v;
                }
            }
        }
    }
    __syncthreads();

    // ---------- phase 1: h1 = tanh(h0 @ W1 + b1) ----------
    // wave: 2 nt x 2 bt; acc = 64 AGPR. Batch-2 super-iters, ROTATED start.
    f32x16 acc1[2][2] = {};   // [bt][t]
    {
        const __bf16* arow0 = h + ln * HSTR + hi * 8;          // bt=0
        const __bf16* arow1 = h + (32 + ln) * HSTR + hi * 8;   // bt=1
        const __bf16* wb0 = w1f + (w * 2 + 0) * 16384 + lofs;
        const __bf16* wb1 = w1f + (w * 2 + 1) * 16384 + lofs;
        for (int ks2 = 0; ks2 < 16; ++ks2) {
            const int ks = (ks2 + ofs16) & 15;   // block-dependent rotation
            bf16x8 aa[2][2], bb[2][2];
#pragma unroll
            for (int u = 0; u < 2; ++u) {
                const int kk = ks * 2 + u;
                const int vo = kk * 512;
                aa[u][0] = *(const bf16x8*)(arow0 + kk * 16);
                aa[u][1] = *(const bf16x8*)(arow1 + kk * 16);
                bb[u][0] = *(const bf16x8*)(wb0 + vo);
                bb[u][1] = *(const bf16x8*)(wb1 + vo);
            }
#pragma unroll
            for (int u = 0; u < 2; ++u) {
#pragma unroll
                for (int t = 0; t < 2; ++t) {
                    acc1[0][t] = __builtin_amdgcn_mfma_f32_32x32x16_bf16(bb[u][t], aa[u][0], acc1[0][t], 0, 0, 0);
                    acc1[1][t] = __builtin_amdgcn_mfma_f32_32x32x16_bf16(bb[u][t], aa[u][1], acc1[1][t], 0, 0, 0);
                }
            }
        }
    }
    __syncthreads();   // all h0 reads done; overwrite in place
#pragma unroll
    for (int t = 0; t < 2; ++t) {
#pragma unroll
        for (int bt = 0; bt < 2; ++bt) {
#pragma unroll
            for (int rg = 0; rg < 4; ++rg) {
                const int n0 = (w * 2 + t) * 32 + 8 * rg + 4 * hi;
                float4 bias = *(const float4*)(b1 + n0);
                bf16x4 v;
                v[0] = (__bf16)fast_tanh(acc1[bt][t][4 * rg + 0] + bias.x);
                v[1] = (__bf16)fast_tanh(acc1[bt][t][4 * rg + 1] + bias.y);
                v[2] = (__bf16)fast_tanh(acc1[bt][t][4 * rg + 2] + bias.z);
                v[3] = (__bf16)fast_tanh(acc1[bt][t][4 * rg + 3] + bias.w);
                *(bf16x4*)(h + (bt * 32 + ln) * HSTR + n0) = v;
            }
        }
    }
    __syncthreads();

    // ---------- phase 2: net = h1 @ W2 + b2 (N pad 160: 5 nt x 2 bt = 10 tiles) ----
    // wave w: tile (nt = w>>1, bt = w&1); waves 0,1 also tile (nt=4, bt=w).
    f32x16 acc2a = {}, acc2e = {};
    const int nt2 = w >> 1;
    const int bt2 = w & 1;
    const bool two = (w < 2);
    {
        const __bf16* arowA = h + (bt2 * 32 + ln) * HSTR + hi * 8;
        const __bf16* arowE = h + ((w & 1) * 32 + ln) * HSTR + hi * 8;  // bt=w for w<2
        const __bf16* wbA = w2f + nt2 * 16384 + lofs;
        const __bf16* wbE = w2f + 4 * 16384 + lofs;
        for (int ks2 = 0; ks2 < 8; ++ks2) {
            const int ks = (ks2 + ofs8) & 7;     // block-dependent rotation
            bf16x8 aaA[2], wA[2], aaE[2], wE[2];
#pragma unroll
            for (int u = 0; u < 2; ++u) {
                const int kk = ks * 4 + u * 2;   // two kk per u-step (batch-2 of pairs)
                const int vo = kk * 512;
                aaA[u] = *(const bf16x8*)(arowA + kk * 16);
                wA[u]  = *(const bf16x8*)(wbA + vo);
                if (two) {
                    aaE[u] = *(const bf16x8*)(arowE + kk * 16);
                    wE[u]  = *(const bf16x8*)(wbE + vo);
                }
            }
            bf16x8 aaA2[2], wA2[2], aaE2[2], wE2[2];
#pragma unroll
            for (int u = 0; u < 2; ++u) {
                const int kk = ks * 4 + u * 2 + 1;
                const int vo = kk * 512;
                aaA2[u] = *(const bf16x8*)(arowA + kk * 16);
                wA2[u]  = *(const bf16x8*)(wbA + vo);
                if (two) {
                    aaE2[u] = *(const bf16x8*)(arowE + kk * 16);
                    wE2[u]  = *(const bf16x8*)(wbE + vo);
                }
            }
#pragma unroll
            for (int u = 0; u < 2; ++u) {
                acc2a = __builtin_amdgcn_mfma_f32_32x32x16_bf16(wA[u], aaA[u], acc2a, 0, 0, 0);
                acc2a = __builtin_amdgcn_mfma_f32_32x32x16_bf16(wA2[u], aaA2[u], acc2a, 0, 0, 0);
                if (two) {
                    acc2e = __builtin_amdgcn_mfma_f32_32x32x16_bf16(wE[u], aaE[u], acc2e, 0, 0, 0);
                    acc2e = __builtin_amdgcn_mfma_f32_32x32x16_bf16(wE2[u], aaE2[u], acc2e, 0, 0, 0);
                }
            }
        }
    }
    __syncthreads();   // all h1 reads done; overwrite with net (fp32)
    {
#pragma unroll
        for (int rg = 0; rg < 4; ++rg) {
            const int n0 = nt2 * 32 + 8 * rg + 4 * hi;   // <= 127 < 136
            float4 bias = *(const float4*)(b2 + n0);
            float4 v;
            v.x = acc2a[4 * rg + 0] + bias.x;
            v.y = acc2a[4 * rg + 1] + bias.y;
            v.z = acc2a[4 * rg + 2] + bias.z;
            v.w = acc2a[4 * rg + 3] + bias.w;
            *(float4*)(net + (bt2 * 32 + ln) * NSTR + n0) = v;
        }
        if (two) {
            // extra tile nt=4 (n 128..135): only rg==0 in range (n0=128/132)
            const int n0 = 128 + 4 * hi;
            float4 bias = *(const float4*)(b2 + n0);
            float4 v;
            v.x = acc2e[0] + bias.x;
            v.y = acc2e[1] + bias.y;
            v.z = acc2e[2] + bias.z;
            v.w = acc2e[3] + bias.w;
            *(float4*)(net + ((w & 1) * 32 + ln) * NSTR + n0) = v;
        }
    }
    __syncthreads();

    // ---------- phase 3: vals = ||M^T x||^2 + eps*||x||^2 ----------
    // 8 threads per row x 64 rows = 512 threads, single pass
    {
        const int r  = tid >> 3;
        const int jg = tid & 7;
        const float* xp = points + (row0 + r) * 16;
        float xv[16];
#pragma unroll
        for (int i = 0; i < 4; ++i) {
            float4 v = ((const float4*)xp)[i];
            xv[i * 4 + 0] = v.x; xv[i * 4 + 1] = v.y;
            xv[i * 4 + 2] = v.z; xv[i * 4 + 3] = v.w;
        }
        float sumsq = 0.f;
#pragma unroll
        for (int i = 0; i < 16; ++i) sumsq += xv[i] * xv[i];
        float p = 0.f;
#pragma unroll
        for (int jj = 0; jj < 2; ++jj) {
            const int j = jg + jj * 8;
            float y = 0.f;
#pragma unroll
            for (int i = 0; i < 16; ++i) {
                float mv = net[r * NSTR + ((i * (i + 1)) >> 1) + j];
                y += (i >= j) ? mv * xv[i] : 0.f;
            }
            p += y * y;
        }
        p += __shfl_xor(p, 1);
        p += __shfl_xor(p, 2);
        p += __shfl_xor(p, 4);
        if (jg == 0) out[row0 + r] = p + 1e-6f * sumsq;
    }
}

extern "C" void kernel_launch(void* const* d_in, const int* in_sizes, int n_in,
                              void* d_out, int out_size, void* d_ws, size_t ws_size,
                              hipStream_t stream) {
    const float* points = (const float*)d_in[0];
    const float* W0 = (const float*)d_in[1];
    const float* b0 = (const float*)d_in[2];
    const float* W1 = (const float*)d_in[3];
    const float* b1 = (const float*)d_in[4];
    const float* W2 = (const float*)d_in[5];
    const float* b2 = (const float*)d_in[6];
    __bf16* ws = (__bf16*)d_ws;
    float* out = (float*)d_out;

    prep_weights<<<(PREP_TOTAL + 255) / 256, 256, 0, stream>>>(W0, W1, W2, ws);

    const int B = in_sizes[0] / 16;   // 131072
    fused_mlp_quad<<<B / 64, 512, 0, stream>>>(points, b0, b1, b2, ws, out);
}